// Round 3
// baseline (2110.872 us; speedup 1.0000x reference)
//
#include <hip/hip_runtime.h>

// Problem constants
#define B_   4
#define L_   2048
#define DIN  1024
#define DOUT 1024
#define H_   16
#define DH_  64
#define M_   (B_ * L_)   // 8192 rows

typedef __bf16 bf16x8 __attribute__((ext_vector_type(8)));
typedef float  f32x4  __attribute__((ext_vector_type(4)));

__device__ __forceinline__ float bf2f(unsigned short u) {
  union { unsigned int i; float f; } x; x.i = ((unsigned int)u) << 16; return x.f;
}
__device__ __forceinline__ unsigned short f2bf(float f) {
  union { float f; unsigned int i; } x; x.f = f;
  unsigned int r = x.i + 0x7FFFu + ((x.i >> 16) & 1u);
  return (unsigned short)(r >> 16);
}

// ---------------------------------------------------------------------------
// C[M,N] = A[M,K] @ W[N,K]^T (+ fp32 bias). fp32 in/out with near-fp32
// precision on matrix cores: per fragment, split x = hi + lo (bf16 each,
// lo = bf16(x - hi), |residual| ~ 1.6e-5 |x|) and accumulate
// hi*hi + lo*hi + hi*lo via v_mfma_f32_16x16x32_bf16 (3 MFMAs / frag pair).
// 128x128 tile, BK=32, 256 thr = 4 waves 2x2, each wave 64x64 as 4x4 16x16.
// Fragment layouts (verified): A/B: idx=lane&15, k=(lane>>4)*8+j;
// C/D: col=lane&15, row=(lane>>4)*4+reg.
// ---------------------------------------------------------------------------
template <typename OutT>
__global__ __launch_bounds__(256, 2)
void gemm_f32split_nt(const float* __restrict__ A,
                      const float* __restrict__ W,
                      OutT* __restrict__ C,
                      const float* __restrict__ bias,
                      int K, int N)
{
  __shared__ float As[128][36];   // +4 pad: 2-way bank alias only (free)
  __shared__ float Bs[128][36];
  const int m0 = blockIdx.x * 128;
  const int n0 = blockIdx.y * 128;
  const int t = threadIdx.x;
  const int w = t >> 6;
  const int lane = t & 63;
  const int wm = (w >> 1) * 64, wn = (w & 1) * 64;
  const int l15 = lane & 15, quad = lane >> 4;

  f32x4 acc[4][4] = {};

  for (int k0 = 0; k0 < K; k0 += 32) {
    // stage 128x32 fp32 tiles of A and W
#pragma unroll
    for (int i = 0; i < 4; i++) {
      int c = t + 256 * i;
      int row = c >> 3;
      int col = (c & 7) * 4;
      *(float4*)(&As[row][col]) = *(const float4*)(A + (size_t)(m0 + row) * K + k0 + col);
      *(float4*)(&Bs[row][col]) = *(const float4*)(W + (size_t)(n0 + row) * K + k0 + col);
    }
    __syncthreads();

    bf16x8 ah[4], al[4], bh[4], bl[4];
#pragma unroll
    for (int i = 0; i < 4; i++) {
      const float* pa = &As[wm + i * 16 + l15][quad * 8];
      const float* pb = &Bs[wn + i * 16 + l15][quad * 8];
      float4 a0 = *(const float4*)(pa);
      float4 a1 = *(const float4*)(pa + 4);
      float4 b0 = *(const float4*)(pb);
      float4 b1 = *(const float4*)(pb + 4);
      float av[8] = {a0.x, a0.y, a0.z, a0.w, a1.x, a1.y, a1.z, a1.w};
      float bv[8] = {b0.x, b0.y, b0.z, b0.w, b1.x, b1.y, b1.z, b1.w};
      union U8 { unsigned short s[8]; bf16x8 v; } uah, ual, ubh, ubl;
#pragma unroll
      for (int j = 0; j < 8; j++) {
        unsigned short hA = f2bf(av[j]);
        unsigned short hB = f2bf(bv[j]);
        uah.s[j] = hA; ual.s[j] = f2bf(av[j] - bf2f(hA));
        ubh.s[j] = hB; ubl.s[j] = f2bf(bv[j] - bf2f(hB));
      }
      ah[i] = uah.v; al[i] = ual.v; bh[i] = ubh.v; bl[i] = ubl.v;
    }

#pragma unroll
    for (int mt = 0; mt < 4; mt++)
#pragma unroll
      for (int nt = 0; nt < 4; nt++) {
        acc[mt][nt] = __builtin_amdgcn_mfma_f32_16x16x32_bf16(ah[mt], bh[nt], acc[mt][nt], 0, 0, 0);
        acc[mt][nt] = __builtin_amdgcn_mfma_f32_16x16x32_bf16(al[mt], bh[nt], acc[mt][nt], 0, 0, 0);
        acc[mt][nt] = __builtin_amdgcn_mfma_f32_16x16x32_bf16(ah[mt], bl[nt], acc[mt][nt], 0, 0, 0);
      }
    __syncthreads();
  }

#pragma unroll
  for (int mt = 0; mt < 4; mt++) {
#pragma unroll
    for (int nt = 0; nt < 4; nt++) {
      int n = n0 + wn + nt * 16 + l15;
      float bv = bias ? bias[n] : 0.0f;
#pragma unroll
      for (int r = 0; r < 4; r++) {
        int m = m0 + wm + mt * 16 + quad * 4 + r;
        float val = acc[mt][nt][r] + bv;
        if constexpr (sizeof(OutT) == 2)
          C[(size_t)m * N + n] = (OutT)f2bf(val);
        else
          C[(size_t)m * N + n] = (OutT)val;
      }
    }
  }
}

// ---------------------------------------------------------------------------
// alpha[r,h] = exp(-exp(A_log[h]) * softplus(x[r]·Wa[h] + dt_bias[h]))
// All fp32. Wa (16x1024 fp32 = 64KB) staged in LDS; one wave per row.
// ---------------------------------------------------------------------------
__global__ __launch_bounds__(256)
void alpha_kernel(const float* __restrict__ x,
                  const float* __restrict__ Wa,
                  const float* __restrict__ dtb,
                  const float* __restrict__ Alg,
                  float* __restrict__ alpha)
{
  __shared__ float WaS[16 * 1024];
  const int t = threadIdx.x;
#pragma unroll
  for (int i = 0; i < 16; i++) {
    int idx = (t + 256 * i) * 4;
    *(float4*)(&WaS[idx]) = *(const float4*)(Wa + idx);
  }
  __syncthreads();
  const int w = t >> 6, lane = t & 63;
  for (int r = blockIdx.x * 4 + w; r < M_; r += gridDim.x * 4) {
    const float* xr = x + (size_t)r * DIN + lane * 16;
    float xv[16];
#pragma unroll
    for (int j = 0; j < 4; j++) {
      float4 a = *(const float4*)(xr + j * 4);
      xv[j * 4 + 0] = a.x; xv[j * 4 + 1] = a.y; xv[j * 4 + 2] = a.z; xv[j * 4 + 3] = a.w;
    }
#pragma unroll 1
    for (int h = 0; h < 16; h++) {
      const float* wr = &WaS[h * 1024 + lane * 16];
      float p = 0.f;
#pragma unroll
      for (int j = 0; j < 4; j++) {
        float4 b = *(const float4*)(wr + j * 4);
        p += xv[j * 4 + 0] * b.x + xv[j * 4 + 1] * b.y +
             xv[j * 4 + 2] * b.z + xv[j * 4 + 3] * b.w;
      }
#pragma unroll
      for (int o = 32; o >= 1; o >>= 1) p += __shfl_xor(p, o, 64);
      if (lane == h) {
        float z = p + dtb[h];
        float sp = (z > 20.f) ? z : log1pf(expf(z));
        alpha[(size_t)r * 16 + h] = expf(-expf(Alg[h]) * sp);
      }
    }
  }
}

// ---------------------------------------------------------------------------
// In-place fp32: q <- q/||q||/8, k <- k/||k||, beta <- sigmoid(beta_raw).
// One wave per (row, head); lane = d within head (DH=64 = wave width).
// ---------------------------------------------------------------------------
__global__ __launch_bounds__(256)
void qkb_kernel(float* __restrict__ q,
                float* __restrict__ k,
                float* __restrict__ bta)
{
  const int t = threadIdx.x, w = t >> 6, lane = t & 63;
  const int NP = M_ * H_;
  for (int p = blockIdx.x * 4 + w; p < NP; p += gridDim.x * 4) {
    size_t off = (size_t)p * 64 + lane;
    float qv = q[off];
    float kv = k[off];
    float bv = bta[off];
    float qs = qv * qv, ks = kv * kv;
#pragma unroll
    for (int o = 32; o >= 1; o >>= 1) {
      qs += __shfl_xor(qs, o, 64);
      ks += __shfl_xor(ks, o, 64);
    }
    q[off] = qv * rsqrtf(qs) * 0.125f;
    k[off] = kv * rsqrtf(ks);
    bta[off] = 1.0f / (1.0f + expf(-bv));
  }
}

// ---------------------------------------------------------------------------
// Sequential scan, fp32 I/O. Block = (b,h); 4 waves; wave w owns d-rows
// [16w,16w+16); lane = e (state column). S[d][e] fp32 in regs.
// ---------------------------------------------------------------------------
__global__ __launch_bounds__(256)
void scan_kernel(const float* __restrict__ q,
                 const float* __restrict__ k,
                 const float* __restrict__ v,
                 const float* __restrict__ bta,
                 const float* __restrict__ alpha,
                 float* __restrict__ ys)
{
  __shared__ float redK[4][64];
  __shared__ float redY[4][64];
  const int bh = blockIdx.x;
  const int b = bh >> 4, h = bh & 15;
  const int t = threadIdx.x, w = t >> 6, e = t & 63;
  const int wbase = __builtin_amdgcn_readfirstlane(w) * 16;

  float S[16];
#pragma unroll
  for (int j = 0; j < 16; j++) S[j] = 0.f;

  const size_t base = (size_t)b * L_ * 1024 + (size_t)h * 64;
  float kf = k[base + e];
  float qf = q[base + e];
  float vf = v[base + e];
  float bf_ = bta[base + e];
  float af = alpha[(size_t)b * L_ * 16 + h];

  for (int ts = 0; ts < L_; ts++) {
    float kcur = kf, qcur = qf, vcur = vf, bcur = bf_, acur = af;
    int nx = (ts + 1 < L_) ? (ts + 1) : ts;
    size_t nb = base + (size_t)nx * 1024;
    kf = k[nb + e]; qf = q[nb + e];
    vf = v[nb + e]; bf_ = bta[nb + e];
    af = alpha[(size_t)b * L_ * 16 + (size_t)nx * 16 + h];

    float ksc[16], qsc[16];
#pragma unroll
    for (int j = 0; j < 16; j++) {
      ksc[j] = __uint_as_float(__builtin_amdgcn_readlane(__float_as_uint(kcur), wbase + j));
      qsc[j] = __uint_as_float(__builtin_amdgcn_readlane(__float_as_uint(qcur), wbase + j));
    }
    float kv = 0.f;
#pragma unroll
    for (int j = 0; j < 16; j++) kv = fmaf(ksc[j], S[j], kv);
    redK[w][e] = kv;
    __syncthreads();
    float kvs = redK[0][e] + redK[1][e] + redK[2][e] + redK[3][e];
    float delta = (vcur - acur * kvs) * bcur;
    float yp = 0.f;
#pragma unroll
    for (int j = 0; j < 16; j++) {
      S[j] = fmaf(acur, S[j], ksc[j] * delta);
      yp = fmaf(qsc[j], S[j], yp);
    }
    redY[w][e] = yp;
    __syncthreads();
    if (w == 0) {
      float y = redY[0][e] + redY[1][e] + redY[2][e] + redY[3][e];
      ys[base + (size_t)ts * 1024 + e] = y;
    }
  }
}

// ---------------------------------------------------------------------------
// ctx = rmsnorm(ys, norm_w) * silu(gate); fp32 in/out; one wave per (row,head).
// ---------------------------------------------------------------------------
__global__ __launch_bounds__(256)
void out_gate_kernel(const float* __restrict__ ys,
                     const float* __restrict__ g,
                     const float* __restrict__ norm_w,
                     float* __restrict__ ctx)
{
  const int t = threadIdx.x, w = t >> 6, lane = t & 63;
  const int NP = M_ * H_;
  float nw = norm_w[lane];
  for (int p = blockIdx.x * 4 + w; p < NP; p += gridDim.x * 4) {
    size_t off = (size_t)p * 64 + lane;
    float y = ys[off];
    float gv = g[off];
    float s = y * y;
#pragma unroll
    for (int o = 32; o >= 1; o >>= 1) s += __shfl_xor(s, o, 64);
    float rs = rsqrtf(s * (1.0f / 64.0f) + 1e-6f);
    float silu = gv / (1.0f + expf(-gv));
    ctx[off] = y * rs * nw * silu;
  }
}

// ---------------------------------------------------------------------------
extern "C" void kernel_launch(void* const* d_in, const int* in_sizes, int n_in,
                              void* d_out, int out_size, void* d_ws, size_t ws_size,
                              hipStream_t stream)
{
  const float* x   = (const float*)d_in[0];
  const float* Wq  = (const float*)d_in[1];
  const float* Wk  = (const float*)d_in[2];
  const float* Wv  = (const float*)d_in[3];
  const float* Wg  = (const float*)d_in[4];
  const float* Wb  = (const float*)d_in[5];
  const float* Wa  = (const float*)d_in[6];
  const float* dtb = (const float*)d_in[7];
  const float* Alg = (const float*)d_in[8];
  const float* nw  = (const float*)d_in[9];
  const float* Wo  = (const float*)d_in[10];
  const float* bo  = (const float*)d_in[11];

  const size_t TSZ = (size_t)M_ * DOUT;   // 8,388,608 elements

  float* q    = (float*)d_ws;
  float* k    = q + TSZ;
  float* v    = k + TSZ;
  float* g    = v + TSZ;
  float* bta  = g + TSZ;
  float* ys   = bta + TSZ;
  float* ctx  = ys + TSZ;
  float* alph = ctx + TSZ;
  float* outp = (float*)d_out;

  dim3 gg(M_ / 128, DOUT / 128);
  gemm_f32split_nt<float><<<gg, 256, 0, stream>>>(x, Wq, q,   nullptr, DIN, DOUT);
  gemm_f32split_nt<float><<<gg, 256, 0, stream>>>(x, Wk, k,   nullptr, DIN, DOUT);
  gemm_f32split_nt<float><<<gg, 256, 0, stream>>>(x, Wv, v,   nullptr, DIN, DOUT);
  gemm_f32split_nt<float><<<gg, 256, 0, stream>>>(x, Wg, g,   nullptr, DIN, DOUT);
  gemm_f32split_nt<float><<<gg, 256, 0, stream>>>(x, Wb, bta, nullptr, DIN, DOUT);
  alpha_kernel<<<128, 256, 0, stream>>>(x, Wa, dtb, Alg, alph);
  qkb_kernel<<<1024, 256, 0, stream>>>(q, k, bta);
  scan_kernel<<<64, 256, 0, stream>>>(q, k, v, bta, alph, ys);
  out_gate_kernel<<<1024, 256, 0, stream>>>(ys, g, nw, ctx);
  gemm_f32split_nt<float><<<gg, 256, 0, stream>>>(ctx, Wo, outp, bo, DOUT, DOUT);
}

// Round 4
// 1778.588 us; speedup vs baseline: 1.1868x; 1.1868x over previous
//
#include <hip/hip_runtime.h>

// Problem constants
#define B_   4
#define L_   2048
#define DIN  1024
#define DOUT 1024
#define H_   16
#define DH_  64
#define M_   (B_ * L_)   // 8192 rows

typedef __bf16 bf16x8 __attribute__((ext_vector_type(8)));
typedef float  f32x4  __attribute__((ext_vector_type(4)));

__device__ __forceinline__ float bf2f(unsigned short u) {
  union { unsigned int i; float f; } x; x.i = ((unsigned int)u) << 16; return x.f;
}
__device__ __forceinline__ unsigned short f2bf(float f) {
  union { float f; unsigned int i; } x; x.f = f;
  unsigned int r = x.i + 0x7FFFu + ((x.i >> 16) & 1u);
  return (unsigned short)(r >> 16);
}

// ---------------------------------------------------------------------------
// fp32 -> (hi, lo) bf16 split: hi = bf16(x), lo = bf16(x - hi).
// Residual ~1.6e-5 |x|. 8 elems/thread, grid-stride.
// ---------------------------------------------------------------------------
__global__ __launch_bounds__(256)
void cast_hilo(const float* __restrict__ in,
               unsigned short* __restrict__ hi,
               unsigned short* __restrict__ lo, int n)
{
  int i = (blockIdx.x * 256 + threadIdx.x) * 8;
  int stride = gridDim.x * 256 * 8;
  for (; i < n; i += stride) {
    float4 a = *(const float4*)(in + i);
    float4 b = *(const float4*)(in + i + 4);
    float v[8] = {a.x, a.y, a.z, a.w, b.x, b.y, b.z, b.w};
    ushort4 h0, h1, l0, l1;
    unsigned short hh[8], ll[8];
#pragma unroll
    for (int j = 0; j < 8; j++) {
      hh[j] = f2bf(v[j]);
      ll[j] = f2bf(v[j] - bf2f(hh[j]));
    }
    h0 = {hh[0], hh[1], hh[2], hh[3]}; h1 = {hh[4], hh[5], hh[6], hh[7]};
    l0 = {ll[0], ll[1], ll[2], ll[3]}; l1 = {ll[4], ll[5], ll[6], ll[7]};
    *(ushort4*)(hi + i) = h0; *(ushort4*)(hi + i + 4) = h1;
    *(ushort4*)(lo + i) = l0; *(ushort4*)(lo + i + 4) = l1;
  }
}

// ---------------------------------------------------------------------------
// GEMM core: C[M,N] = A[M,K] @ W[N,K]^T (+bias) with A,W given as hi/lo bf16
// pairs. acc = hi*hi + lo*hi + hi*lo (3 MFMAs). 128x128 tile, BK=64,
// 256 thr = 4 waves 2x2, each wave 64x64 as 4x4 16x16x32.
// LDS tiles [128][64] ushort, m97-style (no pad).
// Fragment layouts (verified): A/B: idx=lane&15, k=(lane>>4)*8+j;
// C/D: col=lane&15, row=(lane>>4)*4+reg.
// ---------------------------------------------------------------------------
template <typename OutT>
__device__ __forceinline__
void gemm_hilo_core(const unsigned short* __restrict__ Ahi,
                    const unsigned short* __restrict__ Alo,
                    const unsigned short* __restrict__ Whi,
                    const unsigned short* __restrict__ Wlo,
                    OutT* __restrict__ C,
                    const float* __restrict__ bias,
                    int K, int N, int m0, int n0)
{
  __shared__ unsigned short AsH[128][64];
  __shared__ unsigned short AsL[128][64];
  __shared__ unsigned short BsH[128][64];
  __shared__ unsigned short BsL[128][64];
  const int t = threadIdx.x;
  const int w = t >> 6;
  const int lane = t & 63;
  const int wm = (w >> 1) * 64, wn = (w & 1) * 64;
  const int l15 = lane & 15, quad = lane >> 4;

  f32x4 acc[4][4] = {};

  for (int k0 = 0; k0 < K; k0 += 64) {
#pragma unroll
    for (int i = 0; i < 4; i++) {
      int c = t + 256 * i;
      int row = c >> 3;
      int col = (c & 7) * 8;
      size_t ga = (size_t)(m0 + row) * K + k0 + col;
      size_t gb = (size_t)(n0 + row) * K + k0 + col;
      *(uint4*)(&AsH[row][col]) = *(const uint4*)(Ahi + ga);
      *(uint4*)(&AsL[row][col]) = *(const uint4*)(Alo + ga);
      *(uint4*)(&BsH[row][col]) = *(const uint4*)(Whi + gb);
      *(uint4*)(&BsL[row][col]) = *(const uint4*)(Wlo + gb);
    }
    __syncthreads();
#pragma unroll
    for (int kh = 0; kh < 2; kh++) {
      bf16x8 ah[4], al[4], bh[4], bl[4];
#pragma unroll
      for (int i = 0; i < 4; i++) {
        union U { uint4 u; bf16x8 v; } u0, u1, u2, u3;
        u0.u = *(const uint4*)(&AsH[wm + i * 16 + l15][kh * 32 + quad * 8]);
        u1.u = *(const uint4*)(&AsL[wm + i * 16 + l15][kh * 32 + quad * 8]);
        u2.u = *(const uint4*)(&BsH[wn + i * 16 + l15][kh * 32 + quad * 8]);
        u3.u = *(const uint4*)(&BsL[wn + i * 16 + l15][kh * 32 + quad * 8]);
        ah[i] = u0.v; al[i] = u1.v; bh[i] = u2.v; bl[i] = u3.v;
      }
#pragma unroll
      for (int mt = 0; mt < 4; mt++)
#pragma unroll
        for (int nt = 0; nt < 4; nt++) {
          acc[mt][nt] = __builtin_amdgcn_mfma_f32_16x16x32_bf16(ah[mt], bh[nt], acc[mt][nt], 0, 0, 0);
          acc[mt][nt] = __builtin_amdgcn_mfma_f32_16x16x32_bf16(al[mt], bh[nt], acc[mt][nt], 0, 0, 0);
          acc[mt][nt] = __builtin_amdgcn_mfma_f32_16x16x32_bf16(ah[mt], bl[nt], acc[mt][nt], 0, 0, 0);
        }
    }
    __syncthreads();
  }

#pragma unroll
  for (int mt = 0; mt < 4; mt++) {
#pragma unroll
    for (int nt = 0; nt < 4; nt++) {
      int n = n0 + wn + nt * 16 + l15;
      float bv = bias ? bias[n] : 0.0f;
#pragma unroll
      for (int r = 0; r < 4; r++) {
        int m = m0 + wm + mt * 16 + quad * 4 + r;
        C[(size_t)m * N + n] = (OutT)(acc[mt][nt][r] + bv);
      }
    }
  }
}

struct WPtrs {
  const unsigned short* hi[5];
  const unsigned short* lo[5];
};

// Fused 5-projection GEMM: blockIdx.z selects weight/output.
__global__ __launch_bounds__(256, 2)
void proj_gemm(const unsigned short* __restrict__ xhi,
               const unsigned short* __restrict__ xlo,
               WPtrs wp, float* __restrict__ outbase)
{
  int z = blockIdx.z;
  float* C = outbase + (size_t)z * ((size_t)M_ * DOUT);
  gemm_hilo_core<float>(xhi, xlo, wp.hi[z], wp.lo[z], C, nullptr,
                        DIN, DOUT, blockIdx.x * 128, blockIdx.y * 128);
}

__global__ __launch_bounds__(256, 2)
void final_gemm(const unsigned short* __restrict__ chi,
                const unsigned short* __restrict__ clo,
                const unsigned short* __restrict__ whi,
                const unsigned short* __restrict__ wlo,
                float* __restrict__ out, const float* __restrict__ bias)
{
  gemm_hilo_core<float>(chi, clo, whi, wlo, out, bias,
                        DOUT, DOUT, blockIdx.x * 128, blockIdx.y * 128);
}

// ---------------------------------------------------------------------------
// alpha[r,h] = exp(-exp(A_log[h]) * softplus(x[r]·Wa[h] + dt_bias[h]))
// fp32. Wa (64KB) in LDS; one wave per row.
// ---------------------------------------------------------------------------
__global__ __launch_bounds__(256)
void alpha_kernel(const float* __restrict__ x,
                  const float* __restrict__ Wa,
                  const float* __restrict__ dtb,
                  const float* __restrict__ Alg,
                  float* __restrict__ alpha)
{
  __shared__ float WaS[16 * 1024];
  const int t = threadIdx.x;
#pragma unroll
  for (int i = 0; i < 16; i++) {
    int idx = (t + 256 * i) * 4;
    *(float4*)(&WaS[idx]) = *(const float4*)(Wa + idx);
  }
  __syncthreads();
  const int w = t >> 6, lane = t & 63;
  for (int r = blockIdx.x * 4 + w; r < M_; r += gridDim.x * 4) {
    const float* xr = x + (size_t)r * DIN + lane * 16;
    float xv[16];
#pragma unroll
    for (int j = 0; j < 4; j++) {
      float4 a = *(const float4*)(xr + j * 4);
      xv[j * 4 + 0] = a.x; xv[j * 4 + 1] = a.y; xv[j * 4 + 2] = a.z; xv[j * 4 + 3] = a.w;
    }
#pragma unroll 1
    for (int h = 0; h < 16; h++) {
      const float* wr = &WaS[h * 1024 + lane * 16];
      float p = 0.f;
#pragma unroll
      for (int j = 0; j < 4; j++) {
        float4 b = *(const float4*)(wr + j * 4);
        p += xv[j * 4 + 0] * b.x + xv[j * 4 + 1] * b.y +
             xv[j * 4 + 2] * b.z + xv[j * 4 + 3] * b.w;
      }
#pragma unroll
      for (int o = 32; o >= 1; o >>= 1) p += __shfl_xor(p, o, 64);
      if (lane == h) {
        float z = p + dtb[h];
        float sp = (z > 20.f) ? z : log1pf(expf(z));
        alpha[(size_t)r * 16 + h] = expf(-expf(Alg[h]) * sp);
      }
    }
  }
}

// ---------------------------------------------------------------------------
// In-place fp32: q <- q/||q||/8, k <- k/||k||, beta <- sigmoid(beta_raw).
// ---------------------------------------------------------------------------
__global__ __launch_bounds__(256)
void qkb_kernel(float* __restrict__ q,
                float* __restrict__ k,
                float* __restrict__ bta)
{
  const int t = threadIdx.x, w = t >> 6, lane = t & 63;
  const int NP = M_ * H_;
  for (int p = blockIdx.x * 4 + w; p < NP; p += gridDim.x * 4) {
    size_t off = (size_t)p * 64 + lane;
    float qv = q[off];
    float kv = k[off];
    float bv = bta[off];
    float qs = qv * qv, ks = kv * kv;
#pragma unroll
    for (int o = 32; o >= 1; o >>= 1) {
      qs += __shfl_xor(qs, o, 64);
      ks += __shfl_xor(ks, o, 64);
    }
    q[off] = qv * rsqrtf(qs) * 0.125f;
    k[off] = kv * rsqrtf(ks);
    bta[off] = 1.0f / (1.0f + expf(-bv));
  }
}

// ---------------------------------------------------------------------------
// Scan v2: barrier-free, column-parallel.
// Wave = (b, h, group g of 4 e-columns). 16-lane sub-group sg = lane>>4 owns
// column e = 4g + sg; lane i = lane&15 holds d = 4i..4i+3 of S (float4).
// Dots via 4-step shfl_xor butterfly within the 16-lane sub-group.
// No LDS, no __syncthreads. Depth-2 global prefetch. y collected in regs,
// stored every 16 steps (lane (sg,i) -> t0+i, e).
// 1024 waves = 256 blocks; block's 4 waves share (b,h) for L1 reuse of k,q.
// ---------------------------------------------------------------------------
__global__ __launch_bounds__(256)
void scan_kernel(const float* __restrict__ q,
                 const float* __restrict__ k,
                 const float* __restrict__ v,
                 const float* __restrict__ bta,
                 const float* __restrict__ alpha,
                 float* __restrict__ ys)
{
  const int bl = blockIdx.x;
  const int bh = bl >> 2;                    // 64 (b,h) pairs
  const int b = bh >> 4, h = bh & 15;
  const int w = threadIdx.x >> 6;
  const int lane = threadIdx.x & 63;
  const int g = (bl & 3) * 4 + w;            // e-group 0..15
  const int sg = lane >> 4;                  // sub-group = which e of the group
  const int i = lane & 15;                   // d-index: d = 4i..4i+3
  const int e = g * 4 + sg;

  const size_t rowstride = 1024;             // floats per t step (H*DH)
  const size_t bhbase = (size_t)b * L_ * rowstride + (size_t)h * 64;
  const float* kp = k + bhbase + 4 * i;
  const float* qp = q + bhbase + 4 * i;
  const float* vp = v + bhbase + e;
  const float* bp = bta + bhbase + e;
  const float* ap = alpha + (size_t)b * L_ * 16 + h;

  float4 S = {0.f, 0.f, 0.f, 0.f};
  float Yacc = 0.f;

  // depth-2 prefetch buffers
  float4 kbuf[2], qbuf[2];
  float vbuf[2], bbuf[2], abuf[2];
#pragma unroll
  for (int s = 0; s < 2; s++) {
    kbuf[s] = *(const float4*)(kp + s * rowstride);
    qbuf[s] = *(const float4*)(qp + s * rowstride);
    vbuf[s] = vp[s * rowstride];
    bbuf[s] = bp[s * rowstride];
    abuf[s] = ap[s * 16];
  }

  for (int t0 = 0; t0 < L_; t0 += 16) {
#pragma unroll
    for (int tt = 0; tt < 16; tt++) {
      const int sl = tt & 1;
      float4 kc = kbuf[sl];
      float4 qc = qbuf[sl];
      float vc = vbuf[sl], bc = bbuf[sl], ac = abuf[sl];

      // prefetch t+2
      int tn = t0 + tt + 2;
      if (tn > L_ - 1) tn = L_ - 1;
      kbuf[sl] = *(const float4*)(kp + (size_t)tn * rowstride);
      qbuf[sl] = *(const float4*)(qp + (size_t)tn * rowstride);
      vbuf[sl] = vp[(size_t)tn * rowstride];
      bbuf[sl] = bp[(size_t)tn * rowstride];
      abuf[sl] = ap[(size_t)tn * 16];

      // kv = k · S_old  (sum over d)
      float p = kc.x * S.x + kc.y * S.y + kc.z * S.z + kc.w * S.w;
      p += __shfl_xor(p, 1, 64);
      p += __shfl_xor(p, 2, 64);
      p += __shfl_xor(p, 4, 64);
      p += __shfl_xor(p, 8, 64);
      float delta = (vc - ac * p) * bc;
      // S = a*S + k*delta
      S.x = fmaf(ac, S.x, kc.x * delta);
      S.y = fmaf(ac, S.y, kc.y * delta);
      S.z = fmaf(ac, S.z, kc.z * delta);
      S.w = fmaf(ac, S.w, kc.w * delta);
      // y = q · S
      float yp = qc.x * S.x + qc.y * S.y + qc.z * S.z + qc.w * S.w;
      yp += __shfl_xor(yp, 1, 64);
      yp += __shfl_xor(yp, 2, 64);
      yp += __shfl_xor(yp, 4, 64);
      yp += __shfl_xor(yp, 8, 64);
      if (i == tt) Yacc = yp;
    }
    ys[bhbase + (size_t)(t0 + i) * rowstride + e] = Yacc;
  }
}

// ---------------------------------------------------------------------------
// ctx = rmsnorm(ys, norm_w) * silu(gate); fp32, in-place capable.
// ---------------------------------------------------------------------------
__global__ __launch_bounds__(256)
void out_gate_kernel(const float* __restrict__ ys,
                     const float* __restrict__ g,
                     const float* __restrict__ norm_w,
                     float* __restrict__ ctx)
{
  const int t = threadIdx.x, w = t >> 6, lane = t & 63;
  const int NP = M_ * H_;
  float nw = norm_w[lane];
  for (int p = blockIdx.x * 4 + w; p < NP; p += gridDim.x * 4) {
    size_t off = (size_t)p * 64 + lane;
    float y = ys[off];
    float gv = g[off];
    float s = y * y;
#pragma unroll
    for (int o = 32; o >= 1; o >>= 1) s += __shfl_xor(s, o, 64);
    float rs = rsqrtf(s * (1.0f / 64.0f) + 1e-6f);
    float silu = gv / (1.0f + expf(-gv));
    ctx[off] = y * rs * nw * silu;
  }
}

// ---------------------------------------------------------------------------
extern "C" void kernel_launch(void* const* d_in, const int* in_sizes, int n_in,
                              void* d_out, int out_size, void* d_ws, size_t ws_size,
                              hipStream_t stream)
{
  const float* x   = (const float*)d_in[0];
  const float* Wq  = (const float*)d_in[1];
  const float* Wk  = (const float*)d_in[2];
  const float* Wv  = (const float*)d_in[3];
  const float* Wg  = (const float*)d_in[4];
  const float* Wb  = (const float*)d_in[5];
  const float* Wa  = (const float*)d_in[6];
  const float* dtb = (const float*)d_in[7];
  const float* Alg = (const float*)d_in[8];
  const float* nw  = (const float*)d_in[9];
  const float* Wo  = (const float*)d_in[10];
  const float* bo  = (const float*)d_in[11];

  const size_t TSZ = (size_t)M_ * DOUT;   // 8,388,608
  const size_t WSZ = (size_t)DOUT * DIN;  // 1,048,576

  float* q    = (float*)d_ws;             // projections q,k,v,g,bta contiguous
  float* k    = q + TSZ;
  float* v    = k + TSZ;
  float* g    = v + TSZ;
  float* bta  = g + TSZ;
  float* ys   = bta + TSZ;
  float* alph = ys + TSZ;                 // M_*H_ floats
  unsigned short* whl = (unsigned short*)(alph + (size_t)M_ * H_);
  // 12 weight hi/lo buffers of WSZ each (Wq..Wb, Wo)
  unsigned short* whi[6], *wlo[6];
  for (int j = 0; j < 6; j++) { whi[j] = whl + (size_t)(2 * j) * WSZ; wlo[j] = whl + (size_t)(2 * j + 1) * WSZ; }
  // x hi/lo aliased into ys region (dead until scan; casts/proj/alpha run first)
  unsigned short* xhi = (unsigned short*)ys;
  unsigned short* xlo = xhi + TSZ;
  // ctx hi/lo aliased into q region (q dead after scan)
  unsigned short* chi = (unsigned short*)q;
  unsigned short* clo = chi + TSZ;
  float* outp = (float*)d_out;

  // casts
  cast_hilo<<<2048, 256, 0, stream>>>(x, xhi, xlo, (int)TSZ);
  cast_hilo<<<512, 256, 0, stream>>>(Wq, whi[0], wlo[0], (int)WSZ);
  cast_hilo<<<512, 256, 0, stream>>>(Wk, whi[1], wlo[1], (int)WSZ);
  cast_hilo<<<512, 256, 0, stream>>>(Wv, whi[2], wlo[2], (int)WSZ);
  cast_hilo<<<512, 256, 0, stream>>>(Wg, whi[3], wlo[3], (int)WSZ);
  cast_hilo<<<512, 256, 0, stream>>>(Wb, whi[4], wlo[4], (int)WSZ);
  cast_hilo<<<512, 256, 0, stream>>>(Wo, whi[5], wlo[5], (int)WSZ);

  // fused 5-way projection GEMM: z = {q,k,v,g,bta}
  WPtrs wp;
  for (int j = 0; j < 5; j++) { wp.hi[j] = whi[j]; wp.lo[j] = wlo[j]; }
  dim3 gp(M_ / 128, DOUT / 128, 5);
  proj_gemm<<<gp, 256, 0, stream>>>(xhi, xlo, wp, q);

  alpha_kernel<<<128, 256, 0, stream>>>(x, Wa, dtb, Alg, alph);
  qkb_kernel<<<1024, 256, 0, stream>>>(q, k, bta);
  scan_kernel<<<256, 256, 0, stream>>>(q, k, v, bta, alph, ys);
  out_gate_kernel<<<1024, 256, 0, stream>>>(ys, g, nw, ys);  // in-place gate

  // cast ctx (=ys) to hi/lo into q region, then final GEMM
  cast_hilo<<<2048, 256, 0, stream>>>(ys, chi, clo, (int)TSZ);
  dim3 gf(M_ / 128, DOUT / 128);
  final_gemm<<<gf, 256, 0, stream>>>(chi, clo, whi[5], wlo[5], outp, bo);
}

// Round 5
// 1365.050 us; speedup vs baseline: 1.5464x; 1.3029x over previous
//
#include <hip/hip_runtime.h>

// Problem constants
#define B_   4
#define L_   2048
#define DIN  1024
#define DOUT 1024
#define H_   16
#define DH_  64
#define M_   (B_ * L_)   // 8192 rows

typedef __bf16 bf16x8 __attribute__((ext_vector_type(8)));
typedef float  f32x4  __attribute__((ext_vector_type(4)));

__device__ __forceinline__ float bf2f(unsigned short u) {
  union { unsigned int i; float f; } x; x.i = ((unsigned int)u) << 16; return x.f;
}
__device__ __forceinline__ unsigned short f2bf(float f) {
  union { float f; unsigned int i; } x; x.f = f;
  unsigned int r = x.i + 0x7FFFu + ((x.i >> 16) & 1u);
  return (unsigned short)(r >> 16);
}

// DPP-based cross-lane add: x += dpp(x). VALU latency (~5 cyc) instead of the
// ~120-cyc ds_bpermute that __shfl_xor emits. CTRL: 0xB1 = quad_perm[1,0,3,2]
// (xor1), 0x4E = quad_perm[2,3,0,1] (xor2), 0x124 = row_ror:4, 0x128 =
// row_ror:8. B1+4E make all 4 lanes of each quad hold the quad sum; ror:4 +
// ror:8 accumulate the other three quads (each quad counted exactly once) ->
// all 16 lanes of the row hold the 16-lane sum.
template <int CTRL>
__device__ __forceinline__ float dpp_add(float x) {
  int v = __builtin_amdgcn_update_dpp(0, __float_as_int(x), CTRL, 0xF, 0xF, false);
  return x + __int_as_float(v);
}
__device__ __forceinline__ float row16_allreduce(float x) {
  x = dpp_add<0xB1>(x);
  x = dpp_add<0x4E>(x);
  x = dpp_add<0x124>(x);
  x = dpp_add<0x128>(x);
  return x;
}

// ---------------------------------------------------------------------------
// fp32 -> (hi, lo) bf16 split: hi = bf16(x), lo = bf16(x - hi).
// ---------------------------------------------------------------------------
__global__ __launch_bounds__(256)
void cast_hilo(const float* __restrict__ in,
               unsigned short* __restrict__ hi,
               unsigned short* __restrict__ lo, int n)
{
  int i = (blockIdx.x * 256 + threadIdx.x) * 8;
  int stride = gridDim.x * 256 * 8;
  for (; i < n; i += stride) {
    float4 a = *(const float4*)(in + i);
    float4 b = *(const float4*)(in + i + 4);
    float v[8] = {a.x, a.y, a.z, a.w, b.x, b.y, b.z, b.w};
    ushort4 h0, h1, l0, l1;
    unsigned short hh[8], ll[8];
#pragma unroll
    for (int j = 0; j < 8; j++) {
      hh[j] = f2bf(v[j]);
      ll[j] = f2bf(v[j] - bf2f(hh[j]));
    }
    h0 = {hh[0], hh[1], hh[2], hh[3]}; h1 = {hh[4], hh[5], hh[6], hh[7]};
    l0 = {ll[0], ll[1], ll[2], ll[3]}; l1 = {ll[4], ll[5], ll[6], ll[7]};
    *(ushort4*)(hi + i) = h0; *(ushort4*)(hi + i + 4) = h1;
    *(ushort4*)(lo + i) = l0; *(ushort4*)(lo + i + 4) = l1;
  }
}

// ---------------------------------------------------------------------------
// GEMM core: C[M,N] = A[M,K] @ W[N,K]^T (+bias), A/W as hi/lo bf16 pairs.
// acc = hi*hi + lo*hi + hi*lo (3 MFMAs). 128x128 tile, BK=64, 4 waves 2x2.
// ---------------------------------------------------------------------------
template <typename OutT>
__device__ __forceinline__
void gemm_hilo_core(const unsigned short* __restrict__ Ahi,
                    const unsigned short* __restrict__ Alo,
                    const unsigned short* __restrict__ Whi,
                    const unsigned short* __restrict__ Wlo,
                    OutT* __restrict__ C,
                    const float* __restrict__ bias,
                    int K, int N, int m0, int n0)
{
  __shared__ unsigned short AsH[128][64];
  __shared__ unsigned short AsL[128][64];
  __shared__ unsigned short BsH[128][64];
  __shared__ unsigned short BsL[128][64];
  const int t = threadIdx.x;
  const int w = t >> 6;
  const int lane = t & 63;
  const int wm = (w >> 1) * 64, wn = (w & 1) * 64;
  const int l15 = lane & 15, quad = lane >> 4;

  f32x4 acc[4][4] = {};

  for (int k0 = 0; k0 < K; k0 += 64) {
#pragma unroll
    for (int i = 0; i < 4; i++) {
      int c = t + 256 * i;
      int row = c >> 3;
      int col = (c & 7) * 8;
      size_t ga = (size_t)(m0 + row) * K + k0 + col;
      size_t gb = (size_t)(n0 + row) * K + k0 + col;
      *(uint4*)(&AsH[row][col]) = *(const uint4*)(Ahi + ga);
      *(uint4*)(&AsL[row][col]) = *(const uint4*)(Alo + ga);
      *(uint4*)(&BsH[row][col]) = *(const uint4*)(Whi + gb);
      *(uint4*)(&BsL[row][col]) = *(const uint4*)(Wlo + gb);
    }
    __syncthreads();
#pragma unroll
    for (int kh = 0; kh < 2; kh++) {
      bf16x8 ah[4], al[4], bh[4], bl[4];
#pragma unroll
      for (int i = 0; i < 4; i++) {
        union U { uint4 u; bf16x8 v; } u0, u1, u2, u3;
        u0.u = *(const uint4*)(&AsH[wm + i * 16 + l15][kh * 32 + quad * 8]);
        u1.u = *(const uint4*)(&AsL[wm + i * 16 + l15][kh * 32 + quad * 8]);
        u2.u = *(const uint4*)(&BsH[wn + i * 16 + l15][kh * 32 + quad * 8]);
        u3.u = *(const uint4*)(&BsL[wn + i * 16 + l15][kh * 32 + quad * 8]);
        ah[i] = u0.v; al[i] = u1.v; bh[i] = u2.v; bl[i] = u3.v;
      }
#pragma unroll
      for (int mt = 0; mt < 4; mt++)
#pragma unroll
        for (int nt = 0; nt < 4; nt++) {
          acc[mt][nt] = __builtin_amdgcn_mfma_f32_16x16x32_bf16(ah[mt], bh[nt], acc[mt][nt], 0, 0, 0);
          acc[mt][nt] = __builtin_amdgcn_mfma_f32_16x16x32_bf16(al[mt], bh[nt], acc[mt][nt], 0, 0, 0);
          acc[mt][nt] = __builtin_amdgcn_mfma_f32_16x16x32_bf16(ah[mt], bl[nt], acc[mt][nt], 0, 0, 0);
        }
    }
    __syncthreads();
  }

#pragma unroll
  for (int mt = 0; mt < 4; mt++) {
#pragma unroll
    for (int nt = 0; nt < 4; nt++) {
      int n = n0 + wn + nt * 16 + l15;
      float bv = bias ? bias[n] : 0.0f;
#pragma unroll
      for (int r = 0; r < 4; r++) {
        int m = m0 + wm + mt * 16 + quad * 4 + r;
        C[(size_t)m * N + n] = (OutT)(acc[mt][nt][r] + bv);
      }
    }
  }
}

struct WPtrs {
  const unsigned short* hi[5];
  const unsigned short* lo[5];
};

__global__ __launch_bounds__(256, 2)
void proj_gemm(const unsigned short* __restrict__ xhi,
               const unsigned short* __restrict__ xlo,
               WPtrs wp, float* __restrict__ outbase)
{
  int z = blockIdx.z;
  float* C = outbase + (size_t)z * ((size_t)M_ * DOUT);
  gemm_hilo_core<float>(xhi, xlo, wp.hi[z], wp.lo[z], C, nullptr,
                        DIN, DOUT, blockIdx.x * 128, blockIdx.y * 128);
}

__global__ __launch_bounds__(256, 2)
void final_gemm(const unsigned short* __restrict__ chi,
                const unsigned short* __restrict__ clo,
                const unsigned short* __restrict__ whi,
                const unsigned short* __restrict__ wlo,
                float* __restrict__ out, const float* __restrict__ bias)
{
  gemm_hilo_core<float>(chi, clo, whi, wlo, out, bias,
                        DOUT, DOUT, blockIdx.x * 128, blockIdx.y * 128);
}

// ---------------------------------------------------------------------------
// alpha[r,h] = exp(-exp(A_log[h]) * softplus(x[r]·Wa[h] + dt_bias[h]))
// ---------------------------------------------------------------------------
__global__ __launch_bounds__(256)
void alpha_kernel(const float* __restrict__ x,
                  const float* __restrict__ Wa,
                  const float* __restrict__ dtb,
                  const float* __restrict__ Alg,
                  float* __restrict__ alpha)
{
  __shared__ float WaS[16 * 1024];
  const int t = threadIdx.x;
#pragma unroll
  for (int i = 0; i < 16; i++) {
    int idx = (t + 256 * i) * 4;
    *(float4*)(&WaS[idx]) = *(const float4*)(Wa + idx);
  }
  __syncthreads();
  const int w = t >> 6, lane = t & 63;
  for (int r = blockIdx.x * 4 + w; r < M_; r += gridDim.x * 4) {
    const float* xr = x + (size_t)r * DIN + lane * 16;
    float xv[16];
#pragma unroll
    for (int j = 0; j < 4; j++) {
      float4 a = *(const float4*)(xr + j * 4);
      xv[j * 4 + 0] = a.x; xv[j * 4 + 1] = a.y; xv[j * 4 + 2] = a.z; xv[j * 4 + 3] = a.w;
    }
#pragma unroll 1
    for (int h = 0; h < 16; h++) {
      const float* wr = &WaS[h * 1024 + lane * 16];
      float p = 0.f;
#pragma unroll
      for (int j = 0; j < 4; j++) {
        float4 b = *(const float4*)(wr + j * 4);
        p += xv[j * 4 + 0] * b.x + xv[j * 4 + 1] * b.y +
             xv[j * 4 + 2] * b.z + xv[j * 4 + 3] * b.w;
      }
#pragma unroll
      for (int o = 32; o >= 1; o >>= 1) p += __shfl_xor(p, o, 64);
      if (lane == h) {
        float z = p + dtb[h];
        float sp = (z > 20.f) ? z : log1pf(expf(z));
        alpha[(size_t)r * 16 + h] = expf(-expf(Alg[h]) * sp);
      }
    }
  }
}

// ---------------------------------------------------------------------------
// In-place fp32: q <- q/||q||/8, k <- k/||k||, beta <- sigmoid(beta_raw).
// ---------------------------------------------------------------------------
__global__ __launch_bounds__(256)
void qkb_kernel(float* __restrict__ q,
                float* __restrict__ k,
                float* __restrict__ bta)
{
  const int t = threadIdx.x, w = t >> 6, lane = t & 63;
  const int NP = M_ * H_;
  for (int p = blockIdx.x * 4 + w; p < NP; p += gridDim.x * 4) {
    size_t off = (size_t)p * 64 + lane;
    float qv = q[off];
    float kv = k[off];
    float bv = bta[off];
    float qs = qv * qv, ks = kv * kv;
#pragma unroll
    for (int o = 32; o >= 1; o >>= 1) {
      qs += __shfl_xor(qs, o, 64);
      ks += __shfl_xor(ks, o, 64);
    }
    q[off] = qv * rsqrtf(qs) * 0.125f;
    k[off] = kv * rsqrtf(ks);
    bta[off] = 1.0f / (1.0f + expf(-bv));
  }
}

// ---------------------------------------------------------------------------
// Scan v3: barrier-free, column-parallel, DPP reductions.
// Wave = (b, h, group g of 4 e-columns). 16-lane sub-group sg = lane>>4 owns
// column e = 4g + sg; lane i = lane&15 holds d = 4i..4i+3 of S (float4).
// Dots via 4 DPP adds (VALU latency) within the 16-lane row. No LDS, no
// barriers, no DS ops in the dependency chain. Depth-4 global prefetch.
// ---------------------------------------------------------------------------
__global__ __launch_bounds__(256)
void scan_kernel(const float* __restrict__ q,
                 const float* __restrict__ k,
                 const float* __restrict__ v,
                 const float* __restrict__ bta,
                 const float* __restrict__ alpha,
                 float* __restrict__ ys)
{
  const int bl = blockIdx.x;
  const int bh = bl >> 2;                    // 64 (b,h) pairs
  const int b = bh >> 4, h = bh & 15;
  const int w = threadIdx.x >> 6;
  const int lane = threadIdx.x & 63;
  const int g = (bl & 3) * 4 + w;            // e-group 0..15
  const int sg = lane >> 4;                  // which e of the group
  const int i = lane & 15;                   // d-index: d = 4i..4i+3
  const int e = g * 4 + sg;

  const size_t rowstride = 1024;             // floats per t step (H*DH)
  const size_t bhbase = (size_t)b * L_ * rowstride + (size_t)h * 64;
  const float* kp = k + bhbase + 4 * i;
  const float* qp = q + bhbase + 4 * i;
  const float* vp = v + bhbase + e;
  const float* bp = bta + bhbase + e;
  const float* ap = alpha + (size_t)b * L_ * 16 + h;

  float4 S = {0.f, 0.f, 0.f, 0.f};
  float Yacc = 0.f;

  // depth-4 prefetch buffers
  float4 kbuf[4], qbuf[4];
  float vbuf[4], bbuf[4], abuf[4];
#pragma unroll
  for (int s = 0; s < 4; s++) {
    kbuf[s] = *(const float4*)(kp + (size_t)s * rowstride);
    qbuf[s] = *(const float4*)(qp + (size_t)s * rowstride);
    vbuf[s] = vp[(size_t)s * rowstride];
    bbuf[s] = bp[(size_t)s * rowstride];
    abuf[s] = ap[(size_t)s * 16];
  }

  for (int t0 = 0; t0 < L_; t0 += 16) {
#pragma unroll
    for (int tt = 0; tt < 16; tt++) {
      const int sl = tt & 3;
      float4 kc = kbuf[sl];
      float4 qc = qbuf[sl];
      float vc = vbuf[sl], bc = bbuf[sl], ac = abuf[sl];

      // prefetch t+4
      int tn = t0 + tt + 4;
      if (tn > L_ - 1) tn = L_ - 1;
      kbuf[sl] = *(const float4*)(kp + (size_t)tn * rowstride);
      qbuf[sl] = *(const float4*)(qp + (size_t)tn * rowstride);
      vbuf[sl] = vp[(size_t)tn * rowstride];
      bbuf[sl] = bp[(size_t)tn * rowstride];
      abuf[sl] = ap[(size_t)tn * 16];

      // kv = k · S_old (sum over d: 4 in-lane + 16-lane DPP allreduce)
      float p = kc.x * S.x + kc.y * S.y + kc.z * S.z + kc.w * S.w;
      p = row16_allreduce(p);
      float delta = (vc - ac * p) * bc;
      // S = a*S + k*delta
      S.x = fmaf(ac, S.x, kc.x * delta);
      S.y = fmaf(ac, S.y, kc.y * delta);
      S.z = fmaf(ac, S.z, kc.z * delta);
      S.w = fmaf(ac, S.w, kc.w * delta);
      // y = q · S
      float yp = qc.x * S.x + qc.y * S.y + qc.z * S.z + qc.w * S.w;
      yp = row16_allreduce(yp);
      if (i == tt) Yacc = yp;
    }
    ys[bhbase + (size_t)(t0 + i) * rowstride + e] = Yacc;
  }
}

// ---------------------------------------------------------------------------
// ctx = rmsnorm(ys, norm_w) * silu(gate); fp32, in-place capable.
// ---------------------------------------------------------------------------
__global__ __launch_bounds__(256)
void out_gate_kernel(const float* __restrict__ ys,
                     const float* __restrict__ g,
                     const float* __restrict__ norm_w,
                     float* __restrict__ ctx)
{
  const int t = threadIdx.x, w = t >> 6, lane = t & 63;
  const int NP = M_ * H_;
  float nw = norm_w[lane];
  for (int p = blockIdx.x * 4 + w; p < NP; p += gridDim.x * 4) {
    size_t off = (size_t)p * 64 + lane;
    float y = ys[off];
    float gv = g[off];
    float s = y * y;
#pragma unroll
    for (int o = 32; o >= 1; o >>= 1) s += __shfl_xor(s, o, 64);
    float rs = rsqrtf(s * (1.0f / 64.0f) + 1e-6f);
    float silu = gv / (1.0f + expf(-gv));
    ctx[off] = y * rs * nw * silu;
  }
}

// ---------------------------------------------------------------------------
extern "C" void kernel_launch(void* const* d_in, const int* in_sizes, int n_in,
                              void* d_out, int out_size, void* d_ws, size_t ws_size,
                              hipStream_t stream)
{
  const float* x   = (const float*)d_in[0];
  const float* Wq  = (const float*)d_in[1];
  const float* Wk  = (const float*)d_in[2];
  const float* Wv  = (const float*)d_in[3];
  const float* Wg  = (const float*)d_in[4];
  const float* Wb  = (const float*)d_in[5];
  const float* Wa  = (const float*)d_in[6];
  const float* dtb = (const float*)d_in[7];
  const float* Alg = (const float*)d_in[8];
  const float* nw  = (const float*)d_in[9];
  const float* Wo  = (const float*)d_in[10];
  const float* bo  = (const float*)d_in[11];

  const size_t TSZ = (size_t)M_ * DOUT;   // 8,388,608
  const size_t WSZ = (size_t)DOUT * DIN;  // 1,048,576

  float* q    = (float*)d_ws;             // projections q,k,v,g,bta contiguous
  float* k    = q + TSZ;
  float* v    = k + TSZ;
  float* g    = v + TSZ;
  float* bta  = g + TSZ;
  float* ys   = bta + TSZ;
  float* alph = ys + TSZ;                 // M_*H_ floats
  unsigned short* whl = (unsigned short*)(alph + (size_t)M_ * H_);
  unsigned short* whi[6], *wlo[6];
  for (int j = 0; j < 6; j++) { whi[j] = whl + (size_t)(2 * j) * WSZ; wlo[j] = whl + (size_t)(2 * j + 1) * WSZ; }
  // x hi/lo aliased into ys region (dead until scan)
  unsigned short* xhi = (unsigned short*)ys;
  unsigned short* xlo = xhi + TSZ;
  // ctx hi/lo aliased into q region (q dead after scan)
  unsigned short* chi = (unsigned short*)q;
  unsigned short* clo = chi + TSZ;
  float* outp = (float*)d_out;

  cast_hilo<<<2048, 256, 0, stream>>>(x, xhi, xlo, (int)TSZ);
  cast_hilo<<<512, 256, 0, stream>>>(Wq, whi[0], wlo[0], (int)WSZ);
  cast_hilo<<<512, 256, 0, stream>>>(Wk, whi[1], wlo[1], (int)WSZ);
  cast_hilo<<<512, 256, 0, stream>>>(Wv, whi[2], wlo[2], (int)WSZ);
  cast_hilo<<<512, 256, 0, stream>>>(Wg, whi[3], wlo[3], (int)WSZ);
  cast_hilo<<<512, 256, 0, stream>>>(Wb, whi[4], wlo[4], (int)WSZ);
  cast_hilo<<<512, 256, 0, stream>>>(Wo, whi[5], wlo[5], (int)WSZ);

  WPtrs wp;
  for (int j = 0; j < 5; j++) { wp.hi[j] = whi[j]; wp.lo[j] = wlo[j]; }
  dim3 gp(M_ / 128, DOUT / 128, 5);
  proj_gemm<<<gp, 256, 0, stream>>>(xhi, xlo, wp, q);

  alpha_kernel<<<128, 256, 0, stream>>>(x, Wa, dtb, Alg, alph);
  qkb_kernel<<<1024, 256, 0, stream>>>(q, k, bta);
  scan_kernel<<<256, 256, 0, stream>>>(q, k, v, bta, alph, ys);
  out_gate_kernel<<<1024, 256, 0, stream>>>(ys, g, nw, ys);  // in-place gate

  cast_hilo<<<2048, 256, 0, stream>>>(ys, chi, clo, (int)TSZ);
  dim3 gf(M_ / 128, DOUT / 128);
  final_gemm<<<gf, 256, 0, stream>>>(chi, clo, whi[5], wlo[5], outp, bo);
}

// Round 6
// 975.983 us; speedup vs baseline: 2.1628x; 1.3986x over previous
//
#include <hip/hip_runtime.h>

// Problem constants
#define B_   4
#define L_   2048
#define DIN  1024
#define DOUT 1024
#define H_   16
#define DH_  64
#define M_   (B_ * L_)   // 8192 rows

typedef __bf16 bf16x8 __attribute__((ext_vector_type(8)));
typedef float  f32x4  __attribute__((ext_vector_type(4)));

__device__ __forceinline__ float bf2f(unsigned short u) {
  union { unsigned int i; float f; } x; x.i = ((unsigned int)u) << 16; return x.f;
}
__device__ __forceinline__ unsigned short f2bf(float f) {
  union { float f; unsigned int i; } x; x.f = f;
  unsigned int r = x.i + 0x7FFFu + ((x.i >> 16) & 1u);
  return (unsigned short)(r >> 16);
}

// DPP cross-lane add (VALU latency, no DS pipe). 0xB1=quad_perm[1,0,3,2],
// 0x4E=quad_perm[2,3,0,1], 0x124=row_ror:4, 0x128=row_ror:8 -> 16-lane allreduce.
template <int CTRL>
__device__ __forceinline__ float dpp_add(float x) {
  int v = __builtin_amdgcn_update_dpp(0, __float_as_int(x), CTRL, 0xF, 0xF, false);
  return x + __int_as_float(v);
}
__device__ __forceinline__ float row16_allreduce(float x) {
  x = dpp_add<0xB1>(x);
  x = dpp_add<0x4E>(x);
  x = dpp_add<0x124>(x);
  x = dpp_add<0x128>(x);
  return x;
}

// ---------------------------------------------------------------------------
// fp32 -> (hi, lo) bf16 split: hi = bf16(x), lo = bf16(x - hi).
// ---------------------------------------------------------------------------
__global__ __launch_bounds__(256)
void cast_hilo(const float* __restrict__ in,
               unsigned short* __restrict__ hi,
               unsigned short* __restrict__ lo, int n)
{
  int i = (blockIdx.x * 256 + threadIdx.x) * 8;
  int stride = gridDim.x * 256 * 8;
  for (; i < n; i += stride) {
    float4 a = *(const float4*)(in + i);
    float4 b = *(const float4*)(in + i + 4);
    float v[8] = {a.x, a.y, a.z, a.w, b.x, b.y, b.z, b.w};
    ushort4 h0, h1, l0, l1;
    unsigned short hh[8], ll[8];
#pragma unroll
    for (int j = 0; j < 8; j++) {
      hh[j] = f2bf(v[j]);
      ll[j] = f2bf(v[j] - bf2f(hh[j]));
    }
    h0 = {hh[0], hh[1], hh[2], hh[3]}; h1 = {hh[4], hh[5], hh[6], hh[7]};
    l0 = {ll[0], ll[1], ll[2], ll[3]}; l1 = {ll[4], ll[5], ll[6], ll[7]};
    *(ushort4*)(hi + i) = h0; *(ushort4*)(hi + i + 4) = h1;
    *(ushort4*)(lo + i) = l0; *(ushort4*)(lo + i + 4) = l1;
  }
}

// ---------------------------------------------------------------------------
// GEMM core: C[M,N] = A[M,K] @ W[N,K]^T (+bias), A/W as hi/lo bf16 pairs.
// acc = hi*hi + lo*hi + hi*lo (3 MFMAs). 128x128 tile, BK=64, 4 waves 2x2.
// ---------------------------------------------------------------------------
template <typename OutT>
__device__ __forceinline__
void gemm_hilo_core(const unsigned short* __restrict__ Ahi,
                    const unsigned short* __restrict__ Alo,
                    const unsigned short* __restrict__ Whi,
                    const unsigned short* __restrict__ Wlo,
                    OutT* __restrict__ C,
                    const float* __restrict__ bias,
                    int K, int N, int m0, int n0)
{
  __shared__ unsigned short AsH[128][64];
  __shared__ unsigned short AsL[128][64];
  __shared__ unsigned short BsH[128][64];
  __shared__ unsigned short BsL[128][64];
  const int t = threadIdx.x;
  const int w = t >> 6;
  const int lane = t & 63;
  const int wm = (w >> 1) * 64, wn = (w & 1) * 64;
  const int l15 = lane & 15, quad = lane >> 4;

  f32x4 acc[4][4] = {};

  for (int k0 = 0; k0 < K; k0 += 64) {
#pragma unroll
    for (int i = 0; i < 4; i++) {
      int c = t + 256 * i;
      int row = c >> 3;
      int col = (c & 7) * 8;
      size_t ga = (size_t)(m0 + row) * K + k0 + col;
      size_t gb = (size_t)(n0 + row) * K + k0 + col;
      *(uint4*)(&AsH[row][col]) = *(const uint4*)(Ahi + ga);
      *(uint4*)(&AsL[row][col]) = *(const uint4*)(Alo + ga);
      *(uint4*)(&BsH[row][col]) = *(const uint4*)(Whi + gb);
      *(uint4*)(&BsL[row][col]) = *(const uint4*)(Wlo + gb);
    }
    __syncthreads();
#pragma unroll
    for (int kh = 0; kh < 2; kh++) {
      bf16x8 ah[4], al[4], bh[4], bl[4];
#pragma unroll
      for (int i = 0; i < 4; i++) {
        union U { uint4 u; bf16x8 v; } u0, u1, u2, u3;
        u0.u = *(const uint4*)(&AsH[wm + i * 16 + l15][kh * 32 + quad * 8]);
        u1.u = *(const uint4*)(&AsL[wm + i * 16 + l15][kh * 32 + quad * 8]);
        u2.u = *(const uint4*)(&BsH[wn + i * 16 + l15][kh * 32 + quad * 8]);
        u3.u = *(const uint4*)(&BsL[wn + i * 16 + l15][kh * 32 + quad * 8]);
        ah[i] = u0.v; al[i] = u1.v; bh[i] = u2.v; bl[i] = u3.v;
      }
#pragma unroll
      for (int mt = 0; mt < 4; mt++)
#pragma unroll
        for (int nt = 0; nt < 4; nt++) {
          acc[mt][nt] = __builtin_amdgcn_mfma_f32_16x16x32_bf16(ah[mt], bh[nt], acc[mt][nt], 0, 0, 0);
          acc[mt][nt] = __builtin_amdgcn_mfma_f32_16x16x32_bf16(al[mt], bh[nt], acc[mt][nt], 0, 0, 0);
          acc[mt][nt] = __builtin_amdgcn_mfma_f32_16x16x32_bf16(ah[mt], bl[nt], acc[mt][nt], 0, 0, 0);
        }
    }
    __syncthreads();
  }

#pragma unroll
  for (int mt = 0; mt < 4; mt++) {
#pragma unroll
    for (int nt = 0; nt < 4; nt++) {
      int n = n0 + wn + nt * 16 + l15;
      float bv = bias ? bias[n] : 0.0f;
#pragma unroll
      for (int r = 0; r < 4; r++) {
        int m = m0 + wm + mt * 16 + quad * 4 + r;
        C[(size_t)m * N + n] = (OutT)(acc[mt][nt][r] + bv);
      }
    }
  }
}

struct WPtrs {
  const unsigned short* hi[5];
  const unsigned short* lo[5];
};

__global__ __launch_bounds__(256, 2)
void proj_gemm(const unsigned short* __restrict__ xhi,
               const unsigned short* __restrict__ xlo,
               WPtrs wp, float* __restrict__ outbase)
{
  int z = blockIdx.z;
  float* C = outbase + (size_t)z * ((size_t)M_ * DOUT);
  gemm_hilo_core<float>(xhi, xlo, wp.hi[z], wp.lo[z], C, nullptr,
                        DIN, DOUT, blockIdx.x * 128, blockIdx.y * 128);
}

__global__ __launch_bounds__(256, 2)
void final_gemm(const unsigned short* __restrict__ chi,
                const unsigned short* __restrict__ clo,
                const unsigned short* __restrict__ whi,
                const unsigned short* __restrict__ wlo,
                float* __restrict__ out, const float* __restrict__ bias)
{
  gemm_hilo_core<float>(chi, clo, whi, wlo, out, bias,
                        DOUT, DOUT, blockIdx.x * 128, blockIdx.y * 128);
}

// ---------------------------------------------------------------------------
// alpha[r,h] = exp(-exp(A_log[h]) * softplus(x[r]·Wa[h] + dt_bias[h]))
// ---------------------------------------------------------------------------
__global__ __launch_bounds__(256)
void alpha_kernel(const float* __restrict__ x,
                  const float* __restrict__ Wa,
                  const float* __restrict__ dtb,
                  const float* __restrict__ Alg,
                  float* __restrict__ alpha)
{
  __shared__ float WaS[16 * 1024];
  const int t = threadIdx.x;
#pragma unroll
  for (int i = 0; i < 16; i++) {
    int idx = (t + 256 * i) * 4;
    *(float4*)(&WaS[idx]) = *(const float4*)(Wa + idx);
  }
  __syncthreads();
  const int w = t >> 6, lane = t & 63;
  for (int r = blockIdx.x * 4 + w; r < M_; r += gridDim.x * 4) {
    const float* xr = x + (size_t)r * DIN + lane * 16;
    float xv[16];
#pragma unroll
    for (int j = 0; j < 4; j++) {
      float4 a = *(const float4*)(xr + j * 4);
      xv[j * 4 + 0] = a.x; xv[j * 4 + 1] = a.y; xv[j * 4 + 2] = a.z; xv[j * 4 + 3] = a.w;
    }
#pragma unroll 1
    for (int h = 0; h < 16; h++) {
      const float* wr = &WaS[h * 1024 + lane * 16];
      float p = 0.f;
#pragma unroll
      for (int j = 0; j < 4; j++) {
        float4 b = *(const float4*)(wr + j * 4);
        p += xv[j * 4 + 0] * b.x + xv[j * 4 + 1] * b.y +
             xv[j * 4 + 2] * b.z + xv[j * 4 + 3] * b.w;
      }
#pragma unroll
      for (int o = 32; o >= 1; o >>= 1) p += __shfl_xor(p, o, 64);
      if (lane == h) {
        float z = p + dtb[h];
        float sp = (z > 20.f) ? z : log1pf(expf(z));
        alpha[(size_t)r * 16 + h] = expf(-expf(Alg[h]) * sp);
      }
    }
  }
}

// ---------------------------------------------------------------------------
// In-place fp32: q <- q/||q||/8, k <- k/||k||, beta <- sigmoid(beta_raw).
// ---------------------------------------------------------------------------
__global__ __launch_bounds__(256)
void qkb_kernel(float* __restrict__ q,
                float* __restrict__ k,
                float* __restrict__ bta)
{
  const int t = threadIdx.x, w = t >> 6, lane = t & 63;
  const int NP = M_ * H_;
  for (int p = blockIdx.x * 4 + w; p < NP; p += gridDim.x * 4) {
    size_t off = (size_t)p * 64 + lane;
    float qv = q[off];
    float kv = k[off];
    float bv = bta[off];
    float qs = qv * qv, ks = kv * kv;
#pragma unroll
    for (int o = 32; o >= 1; o >>= 1) {
      qs += __shfl_xor(qs, o, 64);
      ks += __shfl_xor(ks, o, 64);
    }
    q[off] = qv * rsqrtf(qs) * 0.125f;
    k[off] = kv * rsqrtf(ks);
    bta[off] = 1.0f / (1.0f + expf(-bv));
  }
}

// ---------------------------------------------------------------------------
// Scan v4: column-parallel + DPP reductions + 8-step window double buffering.
// blockIdx = part*64 + bh so the 4 blocks of one (b,h) are congruent mod 8
// -> same XCD -> shared L2 lines for the k,q rows (HBM once, 3x L2 hit).
// Wave = (b,h,g): sub-group sg owns e=4g+sg; lane i holds d=4i..4i+3.
// Per window: burst-load 8 steps into the idle register set (one latency per
// 8 steps instead of per-step exposure), compute 8 steps from the live set.
// ---------------------------------------------------------------------------
#define WIN 8
__global__ __launch_bounds__(256, 1)
void scan_kernel(const float* __restrict__ q,
                 const float* __restrict__ k,
                 const float* __restrict__ v,
                 const float* __restrict__ bta,
                 const float* __restrict__ alpha,
                 float* __restrict__ ys)
{
  const int bl = blockIdx.x;
  const int bh = bl & 63;                    // XCD-local: parts of bh share L2
  const int part = bl >> 6;                  // 0..3
  const int b = bh >> 4, h = bh & 15;
  const int w = threadIdx.x >> 6;
  const int lane = threadIdx.x & 63;
  const int g = part * 4 + w;                // e-group 0..15
  const int sg = lane >> 4;
  const int i = lane & 15;
  const int e = g * 4 + sg;

  const size_t rowstride = 1024;
  const size_t bhbase = (size_t)b * L_ * rowstride + (size_t)h * 64;
  const float* kp = k + bhbase + 4 * i;
  const float* qp = q + bhbase + 4 * i;
  const float* vp = v + bhbase + e;
  const float* bp = bta + bhbase + e;
  const float* ap = alpha + (size_t)b * L_ * 16 + h;

  float4 S = {0.f, 0.f, 0.f, 0.f};
  float Ya = 0.f, Yb = 0.f;

  float4 kA[WIN], qA[WIN]; float vA[WIN], bA[WIN], aA[WIN];
  float4 kB[WIN], qB[WIN]; float vB[WIN], bB[WIN], aB[WIN];

#define LOADW(KX, QX, VX, BX, AX, T0)                                     \
  {                                                                       \
    _Pragma("unroll")                                                     \
    for (int s = 0; s < WIN; s++) {                                       \
      int ts = (T0) + s; if (ts > L_ - 1) ts = L_ - 1;                    \
      size_t o = (size_t)ts * rowstride;                                  \
      KX[s] = *(const float4*)(kp + o);                                   \
      QX[s] = *(const float4*)(qp + o);                                   \
      VX[s] = vp[o]; BX[s] = bp[o]; AX[s] = ap[(size_t)ts * 16];          \
    }                                                                     \
  }

#define COMPW(KX, QX, VX, BX, AX, T0, YACC)                               \
  {                                                                       \
    _Pragma("unroll")                                                     \
    for (int tt = 0; tt < WIN; tt++) {                                    \
      float4 kc = KX[tt], qc = QX[tt];                                    \
      float vc = VX[tt], bc = BX[tt], ac = AX[tt];                        \
      float p = kc.x * S.x + kc.y * S.y + kc.z * S.z + kc.w * S.w;        \
      p = row16_allreduce(p);                                             \
      float delta = (vc - ac * p) * bc;                                   \
      S.x = fmaf(ac, S.x, kc.x * delta);                                  \
      S.y = fmaf(ac, S.y, kc.y * delta);                                  \
      S.z = fmaf(ac, S.z, kc.z * delta);                                  \
      S.w = fmaf(ac, S.w, kc.w * delta);                                  \
      float yp = qc.x * S.x + qc.y * S.y + qc.z * S.z + qc.w * S.w;       \
      yp = row16_allreduce(yp);                                           \
      if (i == tt) YACC = yp;                                             \
    }                                                                     \
    if (i < WIN)                                                          \
      ys[bhbase + (size_t)((T0) + i) * rowstride + e] = YACC;             \
  }

  LOADW(kA, qA, vA, bA, aA, 0);
  for (int w0 = 0; w0 < L_; w0 += 2 * WIN) {
    LOADW(kB, qB, vB, bB, aB, w0 + WIN);
    COMPW(kA, qA, vA, bA, aA, w0, Ya);
    LOADW(kA, qA, vA, bA, aA, w0 + 2 * WIN);
    COMPW(kB, qB, vB, bB, aB, w0 + WIN, Yb);
  }
#undef LOADW
#undef COMPW
}

// ---------------------------------------------------------------------------
// ctx = rmsnorm(ys, norm_w) * silu(gate); fp32, in-place capable.
// ---------------------------------------------------------------------------
__global__ __launch_bounds__(256)
void out_gate_kernel(const float* __restrict__ ys,
                     const float* __restrict__ g,
                     const float* __restrict__ norm_w,
                     float* __restrict__ ctx)
{
  const int t = threadIdx.x, w = t >> 6, lane = t & 63;
  const int NP = M_ * H_;
  float nw = norm_w[lane];
  for (int p = blockIdx.x * 4 + w; p < NP; p += gridDim.x * 4) {
    size_t off = (size_t)p * 64 + lane;
    float y = ys[off];
    float gv = g[off];
    float s = y * y;
#pragma unroll
    for (int o = 32; o >= 1; o >>= 1) s += __shfl_xor(s, o, 64);
    float rs = rsqrtf(s * (1.0f / 64.0f) + 1e-6f);
    float silu = gv / (1.0f + expf(-gv));
    ctx[off] = y * rs * nw * silu;
  }
}

// ---------------------------------------------------------------------------
extern "C" void kernel_launch(void* const* d_in, const int* in_sizes, int n_in,
                              void* d_out, int out_size, void* d_ws, size_t ws_size,
                              hipStream_t stream)
{
  const float* x   = (const float*)d_in[0];
  const float* Wq  = (const float*)d_in[1];
  const float* Wk  = (const float*)d_in[2];
  const float* Wv  = (const float*)d_in[3];
  const float* Wg  = (const float*)d_in[4];
  const float* Wb  = (const float*)d_in[5];
  const float* Wa  = (const float*)d_in[6];
  const float* dtb = (const float*)d_in[7];
  const float* Alg = (const float*)d_in[8];
  const float* nw  = (const float*)d_in[9];
  const float* Wo  = (const float*)d_in[10];
  const float* bo  = (const float*)d_in[11];

  const size_t TSZ = (size_t)M_ * DOUT;   // 8,388,608
  const size_t WSZ = (size_t)DOUT * DIN;  // 1,048,576

  float* q    = (float*)d_ws;             // projections q,k,v,g,bta contiguous
  float* k    = q + TSZ;
  float* v    = k + TSZ;
  float* g    = v + TSZ;
  float* bta  = g + TSZ;
  float* ys   = bta + TSZ;
  float* alph = ys + TSZ;                 // M_*H_ floats
  unsigned short* whl = (unsigned short*)(alph + (size_t)M_ * H_);
  unsigned short* whi[6], *wlo[6];
  for (int j = 0; j < 6; j++) { whi[j] = whl + (size_t)(2 * j) * WSZ; wlo[j] = whl + (size_t)(2 * j + 1) * WSZ; }
  // x hi/lo aliased into ys region (dead until scan)
  unsigned short* xhi = (unsigned short*)ys;
  unsigned short* xlo = xhi + TSZ;
  // ctx hi/lo aliased into q region (q dead after scan)
  unsigned short* chi = (unsigned short*)q;
  unsigned short* clo = chi + TSZ;
  float* outp = (float*)d_out;

  cast_hilo<<<2048, 256, 0, stream>>>(x, xhi, xlo, (int)TSZ);
  cast_hilo<<<512, 256, 0, stream>>>(Wq, whi[0], wlo[0], (int)WSZ);
  cast_hilo<<<512, 256, 0, stream>>>(Wk, whi[1], wlo[1], (int)WSZ);
  cast_hilo<<<512, 256, 0, stream>>>(Wv, whi[2], wlo[2], (int)WSZ);
  cast_hilo<<<512, 256, 0, stream>>>(Wg, whi[3], wlo[3], (int)WSZ);
  cast_hilo<<<512, 256, 0, stream>>>(Wb, whi[4], wlo[4], (int)WSZ);
  cast_hilo<<<512, 256, 0, stream>>>(Wo, whi[5], wlo[5], (int)WSZ);

  WPtrs wp;
  for (int j = 0; j < 5; j++) { wp.hi[j] = whi[j]; wp.lo[j] = wlo[j]; }
  dim3 gp(M_ / 128, DOUT / 128, 5);
  proj_gemm<<<gp, 256, 0, stream>>>(xhi, xlo, wp, q);

  alpha_kernel<<<128, 256, 0, stream>>>(x, Wa, dtb, Alg, alph);
  qkb_kernel<<<1024, 256, 0, stream>>>(q, k, bta);
  scan_kernel<<<256, 256, 0, stream>>>(q, k, v, bta, alph, ys);
  out_gate_kernel<<<1024, 256, 0, stream>>>(ys, g, nw, ys);  // in-place gate

  cast_hilo<<<2048, 256, 0, stream>>>(ys, chi, clo, (int)TSZ);
  dim3 gf(M_ / 128, DOUT / 128);
  final_gemm<<<gf, 256, 0, stream>>>(chi, clo, whi[5], wlo[5], outp, bo);
}

// Round 7
// 893.419 us; speedup vs baseline: 2.3627x; 1.0924x over previous
//
#include <hip/hip_runtime.h>

// Problem constants
#define B_   4
#define L_   2048
#define DIN  1024
#define DOUT 1024
#define H_   16
#define DH_  64
#define M_   (B_ * L_)   // 8192 rows

typedef __bf16 bf16x8 __attribute__((ext_vector_type(8)));
typedef float  f32x4  __attribute__((ext_vector_type(4)));

__device__ __forceinline__ float bf2f(unsigned short u) {
  union { unsigned int i; float f; } x; x.i = ((unsigned int)u) << 16; return x.f;
}
__device__ __forceinline__ unsigned short f2bf(float f) {
  union { float f; unsigned int i; } x; x.f = f;
  unsigned int r = x.i + 0x7FFFu + ((x.i >> 16) & 1u);
  return (unsigned short)(r >> 16);
}

// DPP cross-lane add (VALU latency, no DS pipe). 0xB1=quad_perm[1,0,3,2],
// 0x4E=quad_perm[2,3,0,1], 0x124=row_ror:4, 0x128=row_ror:8 -> 16-lane allreduce.
template <int CTRL>
__device__ __forceinline__ float dpp_add(float x) {
  int v = __builtin_amdgcn_update_dpp(0, __float_as_int(x), CTRL, 0xF, 0xF, false);
  return x + __int_as_float(v);
}
__device__ __forceinline__ float row16_allreduce(float x) {
  x = dpp_add<0xB1>(x);
  x = dpp_add<0x4E>(x);
  x = dpp_add<0x124>(x);
  x = dpp_add<0x128>(x);
  return x;
}

// ---------------------------------------------------------------------------
// fp32 -> (hi, lo) bf16 split: hi = bf16(x), lo = bf16(x - hi).
// ---------------------------------------------------------------------------
__global__ __launch_bounds__(256)
void cast_hilo(const float* __restrict__ in,
               unsigned short* __restrict__ hi,
               unsigned short* __restrict__ lo, int n)
{
  int i = (blockIdx.x * 256 + threadIdx.x) * 8;
  int stride = gridDim.x * 256 * 8;
  for (; i < n; i += stride) {
    float4 a = *(const float4*)(in + i);
    float4 b = *(const float4*)(in + i + 4);
    float v[8] = {a.x, a.y, a.z, a.w, b.x, b.y, b.z, b.w};
    ushort4 h0, h1, l0, l1;
    unsigned short hh[8], ll[8];
#pragma unroll
    for (int j = 0; j < 8; j++) {
      hh[j] = f2bf(v[j]);
      ll[j] = f2bf(v[j] - bf2f(hh[j]));
    }
    h0 = {hh[0], hh[1], hh[2], hh[3]}; h1 = {hh[4], hh[5], hh[6], hh[7]};
    l0 = {ll[0], ll[1], ll[2], ll[3]}; l1 = {ll[4], ll[5], ll[6], ll[7]};
    *(ushort4*)(hi + i) = h0; *(ushort4*)(hi + i + 4) = h1;
    *(ushort4*)(lo + i) = l0; *(ushort4*)(lo + i + 4) = l1;
  }
}

// ---------------------------------------------------------------------------
// GEMM core: C[M,N] = A[M,K] @ W[N,K]^T (+bias), A/W as hi/lo bf16 pairs.
// acc = hi*hi + lo*hi + hi*lo (3 MFMAs). 128x128 tile, BK=64, 4 waves 2x2.
// LDS rows padded to 72 ushort (144 B = 36 banks): consecutive rows shift by
// 4 banks, so the 16-lane fragment read (same col, rows r..r+15) is 2-way max
// (free) instead of the 16-way conflict (5.7x) of an unpadded 128 B stride.
// ---------------------------------------------------------------------------
#define LPAD 72
template <typename OutT>
__device__ __forceinline__
void gemm_hilo_core(const unsigned short* __restrict__ Ahi,
                    const unsigned short* __restrict__ Alo,
                    const unsigned short* __restrict__ Whi,
                    const unsigned short* __restrict__ Wlo,
                    OutT* __restrict__ C,
                    const float* __restrict__ bias,
                    int K, int N, int m0, int n0)
{
  __shared__ unsigned short AsH[128][LPAD];
  __shared__ unsigned short AsL[128][LPAD];
  __shared__ unsigned short BsH[128][LPAD];
  __shared__ unsigned short BsL[128][LPAD];
  const int t = threadIdx.x;
  const int w = t >> 6;
  const int lane = t & 63;
  const int wm = (w >> 1) * 64, wn = (w & 1) * 64;
  const int l15 = lane & 15, quad = lane >> 4;

  f32x4 acc[4][4] = {};

  for (int k0 = 0; k0 < K; k0 += 64) {
#pragma unroll
    for (int i = 0; i < 4; i++) {
      int c = t + 256 * i;
      int row = c >> 3;
      int col = (c & 7) * 8;
      size_t ga = (size_t)(m0 + row) * K + k0 + col;
      size_t gb = (size_t)(n0 + row) * K + k0 + col;
      *(uint4*)(&AsH[row][col]) = *(const uint4*)(Ahi + ga);
      *(uint4*)(&AsL[row][col]) = *(const uint4*)(Alo + ga);
      *(uint4*)(&BsH[row][col]) = *(const uint4*)(Whi + gb);
      *(uint4*)(&BsL[row][col]) = *(const uint4*)(Wlo + gb);
    }
    __syncthreads();
#pragma unroll
    for (int kh = 0; kh < 2; kh++) {
      bf16x8 ah[4], al[4], bh[4], bl[4];
#pragma unroll
      for (int i = 0; i < 4; i++) {
        union U { uint4 u; bf16x8 v; } u0, u1, u2, u3;
        u0.u = *(const uint4*)(&AsH[wm + i * 16 + l15][kh * 32 + quad * 8]);
        u1.u = *(const uint4*)(&AsL[wm + i * 16 + l15][kh * 32 + quad * 8]);
        u2.u = *(const uint4*)(&BsH[wn + i * 16 + l15][kh * 32 + quad * 8]);
        u3.u = *(const uint4*)(&BsL[wn + i * 16 + l15][kh * 32 + quad * 8]);
        ah[i] = u0.v; al[i] = u1.v; bh[i] = u2.v; bl[i] = u3.v;
      }
#pragma unroll
      for (int mt = 0; mt < 4; mt++)
#pragma unroll
        for (int nt = 0; nt < 4; nt++) {
          acc[mt][nt] = __builtin_amdgcn_mfma_f32_16x16x32_bf16(ah[mt], bh[nt], acc[mt][nt], 0, 0, 0);
          acc[mt][nt] = __builtin_amdgcn_mfma_f32_16x16x32_bf16(al[mt], bh[nt], acc[mt][nt], 0, 0, 0);
          acc[mt][nt] = __builtin_amdgcn_mfma_f32_16x16x32_bf16(ah[mt], bl[nt], acc[mt][nt], 0, 0, 0);
        }
    }
    __syncthreads();
  }

#pragma unroll
  for (int mt = 0; mt < 4; mt++) {
#pragma unroll
    for (int nt = 0; nt < 4; nt++) {
      int n = n0 + wn + nt * 16 + l15;
      float bv = bias ? bias[n] : 0.0f;
#pragma unroll
      for (int r = 0; r < 4; r++) {
        int m = m0 + wm + mt * 16 + quad * 4 + r;
        C[(size_t)m * N + n] = (OutT)(acc[mt][nt][r] + bv);
      }
    }
  }
}

struct WPtrs {
  const unsigned short* hi[5];
  const unsigned short* lo[5];
};

__global__ __launch_bounds__(256, 2)
void proj_gemm(const unsigned short* __restrict__ xhi,
               const unsigned short* __restrict__ xlo,
               WPtrs wp, float* __restrict__ outbase)
{
  int z = blockIdx.z;
  float* C = outbase + (size_t)z * ((size_t)M_ * DOUT);
  gemm_hilo_core<float>(xhi, xlo, wp.hi[z], wp.lo[z], C, nullptr,
                        DIN, DOUT, blockIdx.x * 128, blockIdx.y * 128);
}

__global__ __launch_bounds__(256, 2)
void final_gemm(const unsigned short* __restrict__ chi,
                const unsigned short* __restrict__ clo,
                const unsigned short* __restrict__ whi,
                const unsigned short* __restrict__ wlo,
                float* __restrict__ out, const float* __restrict__ bias)
{
  gemm_hilo_core<float>(chi, clo, whi, wlo, out, bias,
                        DOUT, DOUT, blockIdx.x * 128, blockIdx.y * 128);
}

// ---------------------------------------------------------------------------
// alpha[r,h] = exp(-exp(A_log[h]) * softplus(x[r]·Wa[h] + dt_bias[h]))
// ---------------------------------------------------------------------------
__global__ __launch_bounds__(256)
void alpha_kernel(const float* __restrict__ x,
                  const float* __restrict__ Wa,
                  const float* __restrict__ dtb,
                  const float* __restrict__ Alg,
                  float* __restrict__ alpha)
{
  __shared__ float WaS[16 * 1024];
  const int t = threadIdx.x;
#pragma unroll
  for (int i = 0; i < 16; i++) {
    int idx = (t + 256 * i) * 4;
    *(float4*)(&WaS[idx]) = *(const float4*)(Wa + idx);
  }
  __syncthreads();
  const int w = t >> 6, lane = t & 63;
  for (int r = blockIdx.x * 4 + w; r < M_; r += gridDim.x * 4) {
    const float* xr = x + (size_t)r * DIN + lane * 16;
    float xv[16];
#pragma unroll
    for (int j = 0; j < 4; j++) {
      float4 a = *(const float4*)(xr + j * 4);
      xv[j * 4 + 0] = a.x; xv[j * 4 + 1] = a.y; xv[j * 4 + 2] = a.z; xv[j * 4 + 3] = a.w;
    }
#pragma unroll 1
    for (int h = 0; h < 16; h++) {
      const float* wr = &WaS[h * 1024 + lane * 16];
      float p = 0.f;
#pragma unroll
      for (int j = 0; j < 4; j++) {
        float4 b = *(const float4*)(wr + j * 4);
        p += xv[j * 4 + 0] * b.x + xv[j * 4 + 1] * b.y +
             xv[j * 4 + 2] * b.z + xv[j * 4 + 3] * b.w;
      }
#pragma unroll
      for (int o = 32; o >= 1; o >>= 1) p += __shfl_xor(p, o, 64);
      if (lane == h) {
        float z = p + dtb[h];
        float sp = (z > 20.f) ? z : log1pf(expf(z));
        alpha[(size_t)r * 16 + h] = expf(-expf(Alg[h]) * sp);
      }
    }
  }
}

// ---------------------------------------------------------------------------
// In-place fp32: q <- q/||q||/8, k <- k/||k||, beta <- sigmoid(beta_raw).
// ---------------------------------------------------------------------------
__global__ __launch_bounds__(256)
void qkb_kernel(float* __restrict__ q,
                float* __restrict__ k,
                float* __restrict__ bta)
{
  const int t = threadIdx.x, w = t >> 6, lane = t & 63;
  const int NP = M_ * H_;
  for (int p = blockIdx.x * 4 + w; p < NP; p += gridDim.x * 4) {
    size_t off = (size_t)p * 64 + lane;
    float qv = q[off];
    float kv = k[off];
    float bv = bta[off];
    float qs = qv * qv, ks = kv * kv;
#pragma unroll
    for (int o = 32; o >= 1; o >>= 1) {
      qs += __shfl_xor(qs, o, 64);
      ks += __shfl_xor(ks, o, 64);
    }
    q[off] = qv * rsqrtf(qs) * 0.125f;
    k[off] = kv * rsqrtf(ks);
    bta[off] = 1.0f / (1.0f + expf(-bv));
  }
}

// ---------------------------------------------------------------------------
// Scan v4: column-parallel + DPP reductions + 8-step window double buffering.
// blockIdx = part*64 + bh: the 4 blocks of one (b,h) are congruent mod 8
// -> same XCD -> shared L2 for the k,q rows. Wave=(b,h,g): sub-group sg owns
// e=4g+sg; lane i holds d=4i..4i+3.
// ---------------------------------------------------------------------------
#define WIN 8
__global__ __launch_bounds__(256, 1)
void scan_kernel(const float* __restrict__ q,
                 const float* __restrict__ k,
                 const float* __restrict__ v,
                 const float* __restrict__ bta,
                 const float* __restrict__ alpha,
                 float* __restrict__ ys)
{
  const int bl = blockIdx.x;
  const int bh = bl & 63;
  const int part = bl >> 6;                  // 0..3
  const int b = bh >> 4, h = bh & 15;
  const int w = threadIdx.x >> 6;
  const int lane = threadIdx.x & 63;
  const int g = part * 4 + w;                // e-group 0..15
  const int sg = lane >> 4;
  const int i = lane & 15;
  const int e = g * 4 + sg;

  const size_t rowstride = 1024;
  const size_t bhbase = (size_t)b * L_ * rowstride + (size_t)h * 64;
  const float* kp = k + bhbase + 4 * i;
  const float* qp = q + bhbase + 4 * i;
  const float* vp = v + bhbase + e;
  const float* bp = bta + bhbase + e;
  const float* ap = alpha + (size_t)b * L_ * 16 + h;

  float4 S = {0.f, 0.f, 0.f, 0.f};
  float Ya = 0.f, Yb = 0.f;

  float4 kA[WIN], qA[WIN]; float vA[WIN], bA[WIN], aA[WIN];
  float4 kB[WIN], qB[WIN]; float vB[WIN], bB[WIN], aB[WIN];

#define LOADW(KX, QX, VX, BX, AX, T0)                                     \
  {                                                                       \
    _Pragma("unroll")                                                     \
    for (int s = 0; s < WIN; s++) {                                       \
      int ts = (T0) + s; if (ts > L_ - 1) ts = L_ - 1;                    \
      size_t o = (size_t)ts * rowstride;                                  \
      KX[s] = *(const float4*)(kp + o);                                   \
      QX[s] = *(const float4*)(qp + o);                                   \
      VX[s] = vp[o]; BX[s] = bp[o]; AX[s] = ap[(size_t)ts * 16];          \
    }                                                                     \
  }

#define COMPW(KX, QX, VX, BX, AX, T0, YACC)                               \
  {                                                                       \
    _Pragma("unroll")                                                     \
    for (int tt = 0; tt < WIN; tt++) {                                    \
      float4 kc = KX[tt], qc = QX[tt];                                    \
      float vc = VX[tt], bc = BX[tt], ac = AX[tt];                        \
      float p = kc.x * S.x + kc.y * S.y + kc.z * S.z + kc.w * S.w;        \
      p = row16_allreduce(p);                                             \
      float delta = (vc - ac * p) * bc;                                   \
      S.x = fmaf(ac, S.x, kc.x * delta);                                  \
      S.y = fmaf(ac, S.y, kc.y * delta);                                  \
      S.z = fmaf(ac, S.z, kc.z * delta);                                  \
      S.w = fmaf(ac, S.w, kc.w * delta);                                  \
      float yp = qc.x * S.x + qc.y * S.y + qc.z * S.z + qc.w * S.w;       \
      yp = row16_allreduce(yp);                                           \
      if (i == tt) YACC = yp;                                             \
    }                                                                     \
    if (i < WIN)                                                          \
      ys[bhbase + (size_t)((T0) + i) * rowstride + e] = YACC;             \
  }

  LOADW(kA, qA, vA, bA, aA, 0);
  for (int w0 = 0; w0 < L_; w0 += 2 * WIN) {
    LOADW(kB, qB, vB, bB, aB, w0 + WIN);
    COMPW(kA, qA, vA, bA, aA, w0, Ya);
    LOADW(kA, qA, vA, bA, aA, w0 + 2 * WIN);
    COMPW(kB, qB, vB, bB, aB, w0 + WIN, Yb);
  }
#undef LOADW
#undef COMPW
}

// ---------------------------------------------------------------------------
// ctx = rmsnorm(ys, norm_w) * silu(gate), written directly as hi/lo bf16
// (fuses the ctx cast_hilo pass: saves one 67 MB kernel).
// ---------------------------------------------------------------------------
__global__ __launch_bounds__(256)
void out_gate_kernel(const float* __restrict__ ys,
                     const float* __restrict__ g,
                     const float* __restrict__ norm_w,
                     unsigned short* __restrict__ chi,
                     unsigned short* __restrict__ clo)
{
  const int t = threadIdx.x, w = t >> 6, lane = t & 63;
  const int NP = M_ * H_;
  float nw = norm_w[lane];
  for (int p = blockIdx.x * 4 + w; p < NP; p += gridDim.x * 4) {
    size_t off = (size_t)p * 64 + lane;
    float y = ys[off];
    float gv = g[off];
    float s = y * y;
#pragma unroll
    for (int o = 32; o >= 1; o >>= 1) s += __shfl_xor(s, o, 64);
    float rs = rsqrtf(s * (1.0f / 64.0f) + 1e-6f);
    float silu = gv / (1.0f + expf(-gv));
    float c = y * rs * nw * silu;
    unsigned short hh = f2bf(c);
    chi[off] = hh;
    clo[off] = f2bf(c - bf2f(hh));
  }
}

// ---------------------------------------------------------------------------
extern "C" void kernel_launch(void* const* d_in, const int* in_sizes, int n_in,
                              void* d_out, int out_size, void* d_ws, size_t ws_size,
                              hipStream_t stream)
{
  const float* x   = (const float*)d_in[0];
  const float* Wq  = (const float*)d_in[1];
  const float* Wk  = (const float*)d_in[2];
  const float* Wv  = (const float*)d_in[3];
  const float* Wg  = (const float*)d_in[4];
  const float* Wb  = (const float*)d_in[5];
  const float* Wa  = (const float*)d_in[6];
  const float* dtb = (const float*)d_in[7];
  const float* Alg = (const float*)d_in[8];
  const float* nw  = (const float*)d_in[9];
  const float* Wo  = (const float*)d_in[10];
  const float* bo  = (const float*)d_in[11];

  const size_t TSZ = (size_t)M_ * DOUT;   // 8,388,608
  const size_t WSZ = (size_t)DOUT * DIN;  // 1,048,576

  float* q    = (float*)d_ws;             // projections q,k,v,g,bta contiguous
  float* k    = q + TSZ;
  float* v    = k + TSZ;
  float* g    = v + TSZ;
  float* bta  = g + TSZ;
  float* ys   = bta + TSZ;
  float* alph = ys + TSZ;                 // M_*H_ floats
  unsigned short* whl = (unsigned short*)(alph + (size_t)M_ * H_);
  unsigned short* whi[6], *wlo[6];
  for (int j = 0; j < 6; j++) { whi[j] = whl + (size_t)(2 * j) * WSZ; wlo[j] = whl + (size_t)(2 * j + 1) * WSZ; }
  // x hi/lo aliased into ys region (dead until scan)
  unsigned short* xhi = (unsigned short*)ys;
  unsigned short* xlo = xhi + TSZ;
  // ctx hi/lo aliased into q region (q dead after scan)
  unsigned short* chi = (unsigned short*)q;
  unsigned short* clo = chi + TSZ;
  float* outp = (float*)d_out;

  cast_hilo<<<2048, 256, 0, stream>>>(x, xhi, xlo, (int)TSZ);
  cast_hilo<<<512, 256, 0, stream>>>(Wq, whi[0], wlo[0], (int)WSZ);
  cast_hilo<<<512, 256, 0, stream>>>(Wk, whi[1], wlo[1], (int)WSZ);
  cast_hilo<<<512, 256, 0, stream>>>(Wv, whi[2], wlo[2], (int)WSZ);
  cast_hilo<<<512, 256, 0, stream>>>(Wg, whi[3], wlo[3], (int)WSZ);
  cast_hilo<<<512, 256, 0, stream>>>(Wb, whi[4], wlo[4], (int)WSZ);
  cast_hilo<<<512, 256, 0, stream>>>(Wo, whi[5], wlo[5], (int)WSZ);

  WPtrs wp;
  for (int j = 0; j < 5; j++) { wp.hi[j] = whi[j]; wp.lo[j] = wlo[j]; }
  dim3 gp(M_ / 128, DOUT / 128, 5);
  proj_gemm<<<gp, 256, 0, stream>>>(xhi, xlo, wp, q);

  alpha_kernel<<<128, 256, 0, stream>>>(x, Wa, dtb, Alg, alph);
  qkb_kernel<<<1024, 256, 0, stream>>>(q, k, bta);
  scan_kernel<<<256, 256, 0, stream>>>(q, k, v, bta, alph, ys);
  out_gate_kernel<<<1024, 256, 0, stream>>>(ys, g, nw, chi, clo);

  dim3 gf(M_ / 128, DOUT / 128);
  final_gemm<<<gf, 256, 0, stream>>>(chi, clo, whi[5], wlo[5], outp, bo);
}